// Round 9
// baseline (345.254 us; speedup 1.0000x reference)
//
#include <hip/hip_runtime.h>
#include <math.h>

// Problem constants (from reference): B=4096, D=784, H=16, L=4, R=4, K=8
constexpr int cB   = 4096;
constexpr int cD   = 784;
constexpr int cD1  = 392;
constexpr int cH   = 16;
constexpr int cL   = 4;
constexpr int cR   = 4;
constexpr int cDIN = 1176;            // D1 + D
constexpr int cPDIM = cD1 * 3 * 8;    // 9408 = D1 * 3K
#define LOG2PI_F 1.8378770664093453f
#define L2E_F    1.4426950408889634f   // log2(e)
#define LN2_F    0.6931471805599453f   // ln(2)
#define LN_LN2_F (-0.36651292058166432701f) // ln(ln 2)

__device__ __forceinline__ float rcpf(float x)  { return __builtin_amdgcn_rcpf(x); }
__device__ __forceinline__ float exp2f_(float x){ return __builtin_amdgcn_exp2f(x); }
__device__ __forceinline__ float log2f_(float x){ return __builtin_amdgcn_logf(x); }
__device__ __forceinline__ float expn(float x)  { return exp2f_(x * L2E_F); }   // e^x
__device__ __forceinline__ float logn(float x)  { return log2f_(x) * LN2_F; }   // ln x

// z[b][:] = eps[b][:];  log_q[b] = -0.5*sum(eps^2 + LOG2PI).  One wave/sample.
__global__ void __launch_bounds__(256) init_kernel(const float* __restrict__ eps,
                                                   float* __restrict__ z,
                                                   float* __restrict__ logq) {
    const int wid  = threadIdx.x >> 6;
    const int lane = threadIdx.x & 63;
    const int b = blockIdx.x * 4 + wid;
    const float4* e = (const float4*)(eps + (size_t)b * cD);
    float4* zr = (float4*)(z + (size_t)b * cD);
    float sum = 0.f;
    for (int i = lane; i < cD / 4; i += 64) {   // 784 = 196 float4
        float4 v = e[i];
        zr[i] = v;
        sum = fmaf(v.x, v.x, sum); sum = fmaf(v.y, v.y, sum);
        sum = fmaf(v.z, v.z, sum); sum = fmaf(v.w, v.w, sum);
    }
    #pragma unroll
    for (int off = 32; off; off >>= 1) sum += __shfl_xor(sum, off, 64);
    if (lane == 0) logq[b] = -0.5f * sum - 0.5f * (float)cD * LOG2PI_F;
}

// h[16][b] (transposed) = conditioner MLP on concat(zb, x).
// v4: 4 samples / block (4 waves), split-K 4-way: wave w does rows
// [294*w, +294) for all 4 samples (5-iter K loop).  Grid = B/4 = 1024
// blocks = 4 blocks/CU = 4 waves/SIMD — 2x the latency hiding of v3 at
// identical per-CU W_in traffic.  Partials meet in 1 KB LDS; wave 0 runs
// the residual net (4 samples via its four 16-lane groups).
__global__ void __launch_bounds__(256) mlp_kernel(
    const float* __restrict__ z, const float* __restrict__ x,
    const float* __restrict__ Win, const float* __restrict__ bin,
    const float* __restrict__ W1, const float* __restrict__ b1,
    const float* __restrict__ W2, const float* __restrict__ b2,
    float* __restrict__ hbuf, int zb_off)
{
    __shared__ float part[4][4][16];   // [wave][sample][col]
    const int wid  = threadIdx.x >> 6;
    const int lane = threadIdx.x & 63;
    const int j = lane & 15;
    const int G = lane >> 4;                      // 16-lane group 0..3
    const int bs = blockIdx.x * 4;                // block's 4 samples
    const int r0 = wid * 294;                     // wave's row range

    float acc[4][16];
    #pragma unroll
    for (int s = 0; s < 4; ++s)
        #pragma unroll
        for (int c = 0; c < 16; ++c) acc[s][c] = 0.f;

    const float* pz[4]; const float* px[4];
    #pragma unroll
    for (int s = 0; s < 4; ++s) {
        pz[s] = z + (size_t)(bs + s) * cD + zb_off;
        px[s] = x + (size_t)(bs + s) * cD - cD1;   // valid for i>=cD1
    }

    for (int i = r0 + lane; i < r0 + 294; i += 64) {
        const float4* wr = (const float4*)(Win + (size_t)i * cH);
        float4 w0 = wr[0], w1 = wr[1], w2 = wr[2], w3 = wr[3];
        float wv[16] = {w0.x,w0.y,w0.z,w0.w, w1.x,w1.y,w1.z,w1.w,
                        w2.x,w2.y,w2.z,w2.w, w3.x,w3.y,w3.z,w3.w};
        #pragma unroll
        for (int s = 0; s < 4; ++s) {
            const float* src = (i < cD1) ? pz[s] : px[s];
            float v = src[i];
            #pragma unroll
            for (int c = 0; c < 16; ++c) acc[s][c] = fmaf(v, wv[c], acc[s][c]);
        }
    }

    // Per-sample transpose-reduce (stages 8,4,2,1): lane ends holding col
    // (lane&15) of sample s, partial over its 16-lane group.
    #pragma unroll
    for (int s = 0; s < 4; ++s) {
        #pragma unroll
        for (int c = 0; c < 8; ++c) {
            float sent = (lane & 8) ? acc[s][c] : acc[s][c + 8];
            float mine = (lane & 8) ? acc[s][c + 8] : acc[s][c];
            acc[s][c] = mine + __shfl_xor(sent, 8, 64);
        }
        #pragma unroll
        for (int c = 0; c < 4; ++c) {
            float sent = (lane & 4) ? acc[s][c] : acc[s][c + 4];
            float mine = (lane & 4) ? acc[s][c + 4] : acc[s][c];
            acc[s][c] = mine + __shfl_xor(sent, 4, 64);
        }
        #pragma unroll
        for (int c = 0; c < 2; ++c) {
            float sent = (lane & 2) ? acc[s][c] : acc[s][c + 2];
            float mine = (lane & 2) ? acc[s][c + 2] : acc[s][c];
            acc[s][c] = mine + __shfl_xor(sent, 2, 64);
        }
        {
            float sent = (lane & 1) ? acc[s][0] : acc[s][1];
            float mine = (lane & 1) ? acc[s][1] : acc[s][0];
            acc[s][0] = mine + __shfl_xor(sent, 1, 64);
        }
    }
    // Route sample G to group G while finishing the cross-group reduction.
    const int g4 = (lane >> 4) & 1, g5 = (lane >> 5) & 1;
    float a01, a23, colsum;
    {
        float sent = g4 ? acc[0][0] : acc[1][0];
        float keep = g4 ? acc[1][0] : acc[0][0];
        a01 = keep + __shfl_xor(sent, 16, 64);
    }
    {
        float sent = g4 ? acc[2][0] : acc[3][0];
        float keep = g4 ? acc[3][0] : acc[2][0];
        a23 = keep + __shfl_xor(sent, 16, 64);
    }
    {
        float sent = g5 ? a01 : a23;
        float keep = g5 ? a23 : a01;
        colsum = keep + __shfl_xor(sent, 32, 64);   // group G owns sample G
    }

    part[wid][G][j] = colsum;
    __syncthreads();
    if (wid != 0) return;

    colsum = part[0][G][j] + part[1][G][j] + part[2][G][j] + part[3][G][j];

    float t0 = colsum + bin[j];
    float hj = t0 * rcpf(1.0f + expn(-t0));   // square_swish

    #pragma unroll
    for (int r = 0; r < cR; ++r) {
        const float* w1r = W1 + r * 256;
        const float* w2r = W2 + r * 256;
        float u = b1[r * 16 + j];
        #pragma unroll
        for (int i = 0; i < 16; ++i)
            u = fmaf(__shfl(hj, i, 16), w1r[i * 16 + j], u);
        u = u * rcpf(1.0f + expn(-u));
        float v = b2[r * 16 + j];
        #pragma unroll
        for (int i = 0; i < 16; ++i)
            v = fmaf(__shfl(u, i, 16), w2r[i * 16 + j], v);
        hj += v;
    }
    hbuf[(size_t)j * cB + (bs + G)] = hj;   // transposed: [16][B]
}

// Invert the logistic-mixture logit per (sample b, dim d).
// Block = 256: 4 waves = 4 consecutive d (wave-uniform), lane = b in a 64-tile.
__global__ void __launch_bounds__(256) invert_kernel(
    float* __restrict__ z, const float* __restrict__ hbuf,
    const float* __restrict__ Wo, const float* __restrict__ bo,
    float* __restrict__ logq, int za_off)
{
    const int wid  = threadIdx.x >> 6;
    const int lane = threadIdx.x & 63;
    const int d = __builtin_amdgcn_readfirstlane(blockIdx.x * 4 + wid); // uniform
    const int b = blockIdx.y * 64 + lane;

    // h: 16 coalesced loads from transposed hbuf
    float hh[16];
    #pragma unroll
    for (int i = 0; i < 16; ++i) hh[i] = hbuf[(size_t)i * cB + b];

    // p[24] = bo[d*24+j] + sum_i h[i]*Wo[i*9408 + d*24 + j]  (Wo wave-uniform)
    float p[24];
    {
        const float4* bp = (const float4*)(bo + (size_t)d * 24);
        #pragma unroll
        for (int j4 = 0; j4 < 6; ++j4) {
            float4 v = bp[j4];
            p[j4*4+0] = v.x; p[j4*4+1] = v.y; p[j4*4+2] = v.z; p[j4*4+3] = v.w;
        }
        #pragma unroll
        for (int i = 0; i < 16; ++i) {
            float hv = hh[i];
            const float4* wr = (const float4*)(Wo + (size_t)i * cPDIM + (size_t)d * 24);
            #pragma unroll
            for (int j4 = 0; j4 < 6; ++j4) {
                float4 wv = wr[j4];
                p[j4*4+0] = fmaf(hv, wv.x, p[j4*4+0]);
                p[j4*4+1] = fmaf(hv, wv.y, p[j4*4+1]);
                p[j4*4+2] = fmaf(hv, wv.z, p[j4*4+2]);
                p[j4*4+3] = fmaf(hv, wv.w, p[j4*4+3]);
            }
        }
    }

    // Mirror: solve with mu_bar = sgn*mu, yb = |y|; x = sgn*x_bar.
    const float y0  = z[(size_t)b * cD + za_off + d];
    const float sgn = (y0 < 0.f) ? -1.f : 1.f;
    const float yb  = fabsf(y0);

    // Unnormalized softmax weights wt (sum S); per-k prescaled scales.
    float wt[8], pm[8], q2[8], is2[8], nm2[8], wis2[8];
    float S, lgSn, SLN2, lo, hi;
    {
        float m = p[0];
        #pragma unroll
        for (int k = 1; k < 8; ++k) m = fmaxf(m, p[k]);
        S = 0.f;
        #pragma unroll
        for (int k = 0; k < 8; ++k) {
            pm[k] = p[k] - m;
            wt[k] = exp2f_(pm[k] * L2E_F);
            S += wt[k];
        }
        lgSn = log2f_(S) * LN2_F;   // ln S
        SLN2 = S * LN2_F;
        float lo0 = 1e30f, hi0 = -1e30f;
        #pragma unroll
        for (int k = 0; k < 8; ++k) {
            q2[k] = p[16 + k] * L2E_F;          // log2 s_k
            float sk  = exp2f_(q2[k]);          // s_k
            float ik  = exp2f_(-q2[k]);         // 1/s_k
            is2[k] = ik * L2E_F;
            float mub = sgn * p[8 + k];
            nm2[k] = -mub * is2[k];
            wis2[k] = wt[k] * is2[k];
            float inv = fmaf(yb, sk, mub);      // mu_bar + s_k*yb
            lo0 = fminf(lo0, inv); hi0 = fmaxf(hi0, inv);
        }
        float pad = 1e-3f + 1e-5f * (fabsf(lo0) + fabsf(hi0));
        lo = lo0 - pad; hi = hi0 + pad;
    }

    float xv, ld;
    if (yb <= 30.0f) {
        // tau*S with tau = sigmoid(-yb) >= ~5e-14
        float et   = exp2f_(-yb * L2E_F);
        float tauS = et * rcpf(1.0f + et) * S;
        // --- 2 bisections; sn = 1/(1+exp2(t2)) is overflow-exact (inf->0)
        #pragma unroll 1
        for (int it = 0; it < 2; ++it) {
            float mid = 0.5f * (lo + hi);
            float sfv = 0.f;
            #pragma unroll
            for (int k = 0; k < 8; ++k) {
                float t2 = fmaf(mid, is2[k], nm2[k]);
                float e  = exp2f_(t2);
                float r  = rcpf(1.0f + e);
                sfv = fmaf(wt[k], r, sfv);
            }
            if (sfv > tauS) lo = mid; else hi = mid;   // sf decreasing in x
        }
        // --- 3 bracketed Newton steps (quadratic from bracket/4 midpoint)
        xv = 0.5f * (lo + hi);
        #pragma unroll 1
        for (int it = 0; it < 3; ++it) {
            float cdf = 0.f, sfv = 0.f, pdfa = 0.f;
            #pragma unroll
            for (int k = 0; k < 8; ++k) {
                float t2 = fmaf(xv, is2[k], nm2[k]);
                float e  = exp2f_(-fabsf(t2));
                float r  = rcpf(1.0f + e);
                float a  = e * r;
                float sp = (t2 >= 0.f) ? r : a;
                float sn = (t2 >= 0.f) ? a : r;
                cdf = fmaf(wt[k], sp, cdf);
                sfv = fmaf(wt[k], sn, sfv);
                pdfa = fmaf(wis2[k], sp * sn, pdfa);
            }
            float f = (log2f_(cdf) - log2f_(sfv)) * LN2_F;
            if (f < yb) lo = xv; else hi = xv;
            float step = (f - yb) * cdf * sfv * rcpf(pdfa * SLN2);
            float xn = xv - step;
            if (!(xn > lo && xn < hi)) xn = 0.5f * (lo + hi);
            xv = xn;
        }
        // --- peeled eval: ld at xv (pre-step; step ~ eps) + final step
        {
            float cdf = 0.f, sfv = 0.f, pdfa = 0.f;
            #pragma unroll
            for (int k = 0; k < 8; ++k) {
                float t2 = fmaf(xv, is2[k], nm2[k]);
                float e  = exp2f_(-fabsf(t2));
                float r  = rcpf(1.0f + e);
                float a  = e * r;
                float sp = (t2 >= 0.f) ? r : a;
                float sn = (t2 >= 0.f) ? a : r;
                cdf = fmaf(wt[k], sp, cdf);
                sfv = fmaf(wt[k], sn, sfv);
                pdfa = fmaf(wis2[k], sp * sn, pdfa);
            }
            float l2c = log2f_(cdf), l2s = log2f_(sfv), l2p = log2f_(pdfa);
            ld = (l2p - l2c - l2s) * LN2_F + LN_LN2_F + lgSn;
            float f = (l2c - l2s) * LN2_F;
            if (f < yb) lo = xv; else hi = xv;
            float step = (f - yb) * cdf * sfv * rcpf(pdfa * SLN2);
            float xn = xv - step;
            if (!(xn > lo && xn < hi)) xn = 0.5f * (lo + hi);
            xv = xn;
        }
    } else {
        // --- tail (yb>30): log-space LSE Newton from exact-bracket midpoint;
        // lc = log(1-sf) ~ -e^{-yb} ~ 0 (dropped, error < 1e-13).
        float lw[8], lis[8];
        #pragma unroll
        for (int k = 0; k < 8; ++k) {
            lw[k]  = pm[k] - lgSn;       // log softmax weight
            lis[k] = -q2[k] * LN2_F;     // -log s_k
        }
        xv = 0.5f * (lo + hi);
        #pragma unroll 1
        for (int it = 0; it < 4; ++it) {
            float u[8];
            float mu_ = -1e30f;
            #pragma unroll
            for (int k = 0; k < 8; ++k) {
                float t  = fmaf(xv, is2[k], nm2[k]) * LN2_F;  // natural t
                float ec = fminf(expn(-t), 1.0f);
                // log sigmoid(-t) = -t - log1p(e^{-t}) ~ -t - (ec - ec^2/2)
                u[k] = lw[k] - t - ec * fmaf(-0.5f, ec, 1.0f);
                mu_ = fmaxf(mu_, u[k]);
            }
            float Su = 0.f;
            #pragma unroll
            for (int k = 0; k < 8; ++k) Su += expn(u[k] - mu_);
            float lsf = mu_ + logn(Su);
            float m2 = -1e30f;
            #pragma unroll
            for (int k = 0; k < 8; ++k) m2 = fmaxf(m2, u[k] + lis[k]);
            float S2 = 0.f;
            #pragma unroll
            for (int k = 0; k < 8; ++k) S2 += expn(u[k] + lis[k] - m2);
            float lp = m2 + logn(S2);
            if (it == 3) { ld = lp - lsf; break; }
            float f = -lsf;                       // lc ~ 0
            if (f < yb) lo = xv; else hi = xv;
            float step = (f - yb) * expn(lsf - lp);
            float xn = xv - step;
            if (!(xn > lo && xn < hi)) xn = 0.5f * (lo + hi);
            xv = xn;
        }
    }

    z[(size_t)b * cD + za_off + d] = sgn * xv;

    // reduce ld over the 4 waves (4 d's) per b, one atomic per (block, b)
    __shared__ float red[256];
    red[threadIdx.x] = ld;
    __syncthreads();
    if (wid == 0) {
        float ssum = red[lane] + red[lane + 64] + red[lane + 128] + red[lane + 192];
        atomicAdd(&logq[b], ssum);
    }
}

extern "C" void kernel_launch(void* const* d_in, const int* in_sizes, int n_in,
                              void* d_out, int out_size, void* d_ws, size_t ws_size,
                              hipStream_t stream) {
    const float* x     = (const float*)d_in[0];
    const float* eps   = (const float*)d_in[1];
    const float* W_in  = (const float*)d_in[2];
    const float* b_in  = (const float*)d_in[3];
    const float* W1    = (const float*)d_in[4];
    const float* b1    = (const float*)d_in[5];
    const float* W2    = (const float*)d_in[6];
    const float* b2    = (const float*)d_in[7];
    const float* W_out = (const float*)d_in[8];
    const float* b_out = (const float*)d_in[9];

    float* z    = (float*)d_out;              // (B, D) working state = output z
    float* logq = z + (size_t)cB * cD;        // (B,)   output log_q
    float* hbuf = (float*)d_ws;               // (16, B) transposed scratch

    init_kernel<<<cB / 4, 256, 0, stream>>>(eps, z, logq);

    for (int l = cL - 1; l >= 0; --l) {
        const int zb_off = (l & 1) ? 0 : cD1;   // zb half offset within z row
        const int za_off = (l & 1) ? cD1 : 0;   // za half (overwritten in place)
        mlp_kernel<<<cB / 4, 256, 0, stream>>>(
            z, x,
            W_in + (size_t)l * cDIN * cH, b_in + (size_t)l * cH,
            W1 + (size_t)l * cR * cH * cH, b1 + (size_t)l * cR * cH,
            W2 + (size_t)l * cR * cH * cH, b2 + (size_t)l * cR * cH,
            hbuf, zb_off);
        invert_kernel<<<dim3(cD1 / 4, cB / 64), 256, 0, stream>>>(
            z, hbuf,
            W_out + (size_t)l * cH * cPDIM, b_out + (size_t)l * cPDIM,
            logq, za_off);
    }
}

// Round 10
// 299.389 us; speedup vs baseline: 1.1532x; 1.1532x over previous
//
#include <hip/hip_runtime.h>
#include <math.h>

// Problem constants (from reference): B=4096, D=784, H=16, L=4, R=4, K=8
constexpr int cB   = 4096;
constexpr int cD   = 784;
constexpr int cD1  = 392;
constexpr int cH   = 16;
constexpr int cL   = 4;
constexpr int cR   = 4;
constexpr int cDIN = 1176;            // D1 + D
constexpr int cPDIM = cD1 * 3 * 8;    // 9408 = D1 * 3K
#define LOG2PI_F 1.8378770664093453f
#define L2E_F    1.4426950408889634f   // log2(e)
#define LN2_F    0.6931471805599453f   // ln(2)
#define LN_LN2_F (-0.36651292058166432701f) // ln(ln 2)

__device__ __forceinline__ float rcpf(float x)  { return __builtin_amdgcn_rcpf(x); }
__device__ __forceinline__ float exp2f_(float x){ return __builtin_amdgcn_exp2f(x); }
__device__ __forceinline__ float log2f_(float x){ return __builtin_amdgcn_logf(x); }
__device__ __forceinline__ float expn(float x)  { return exp2f_(x * L2E_F); }   // e^x
__device__ __forceinline__ float logn(float x)  { return log2f_(x) * LN2_F; }   // ln x

// log_q[b] = -0.5*sum(eps^2 + LOG2PI).  One wave/sample.  (No z copy: the
// four invert launches write every z element, layers 3/2 read y from eps.)
__global__ void __launch_bounds__(256) init_kernel(const float* __restrict__ eps,
                                                   float* __restrict__ logq) {
    const int wid  = threadIdx.x >> 6;
    const int lane = threadIdx.x & 63;
    const int b = blockIdx.x * 4 + wid;
    const float4* e = (const float4*)(eps + (size_t)b * cD);
    float sum = 0.f;
    for (int i = lane; i < cD / 4; i += 64) {   // 784 = 196 float4
        float4 v = e[i];
        sum = fmaf(v.x, v.x, sum); sum = fmaf(v.y, v.y, sum);
        sum = fmaf(v.z, v.z, sum); sum = fmaf(v.w, v.w, sum);
    }
    #pragma unroll
    for (int off = 32; off; off >>= 1) sum += __shfl_xor(sum, off, 64);
    if (lane == 0) logq[b] = -0.5f * sum - 0.5f * (float)cD * LOG2PI_F;
}

// h[16][b] (transposed) = conditioner MLP on concat(zb, x).
// v3 (best measured): 8 samples / block (4 waves).  Wave w: rows
// [588*(w>>1), +588) for samples (w&1)*4..+3 — split-K across wave pairs.
// Partials meet in 1 KB LDS; waves 0-1 run the residual net (4 samples each
// via width-16 shuffles).  zbsrc points at the zb half (z or eps).
__global__ void __launch_bounds__(256) mlp_kernel(
    const float* __restrict__ zbsrc, const float* __restrict__ x,
    const float* __restrict__ Win, const float* __restrict__ bin,
    const float* __restrict__ W1, const float* __restrict__ b1,
    const float* __restrict__ W2, const float* __restrict__ b2,
    float* __restrict__ hbuf)
{
    __shared__ float part[4][4][16];   // [wave][sample-in-group][col]
    const int wid  = threadIdx.x >> 6;
    const int lane = threadIdx.x & 63;
    const int j = lane & 15;
    const int G = lane >> 4;                      // 16-lane group 0..3
    const int bs = blockIdx.x * 8;                // block's first sample
    const int sb = bs + (wid & 1) * 4;            // wave's first sample
    const int r0 = (wid >> 1) * 588;              // wave's row range start

    float acc[4][16];
    #pragma unroll
    for (int s = 0; s < 4; ++s)
        #pragma unroll
        for (int c = 0; c < 16; ++c) acc[s][c] = 0.f;

    const float* pz[4]; const float* px[4];
    #pragma unroll
    for (int s = 0; s < 4; ++s) {
        pz[s] = zbsrc + (size_t)(sb + s) * cD;
        px[s] = x + (size_t)(sb + s) * cD - cD1;   // valid for i>=cD1
    }

    for (int i = r0 + lane; i < r0 + 588; i += 64) {
        const float4* wr = (const float4*)(Win + (size_t)i * cH);
        float4 w0 = wr[0], w1 = wr[1], w2 = wr[2], w3 = wr[3];
        float wv[16] = {w0.x,w0.y,w0.z,w0.w, w1.x,w1.y,w1.z,w1.w,
                        w2.x,w2.y,w2.z,w2.w, w3.x,w3.y,w3.z,w3.w};
        #pragma unroll
        for (int s = 0; s < 4; ++s) {
            const float* src = (i < cD1) ? pz[s] : px[s];
            float v = src[i];
            #pragma unroll
            for (int c = 0; c < 16; ++c) acc[s][c] = fmaf(v, wv[c], acc[s][c]);
        }
    }

    // Per-sample transpose-reduce (stages 8,4,2,1): lane ends holding col
    // (lane&15) of sample s, partial over its 16-lane group.
    #pragma unroll
    for (int s = 0; s < 4; ++s) {
        #pragma unroll
        for (int c = 0; c < 8; ++c) {
            float sent = (lane & 8) ? acc[s][c] : acc[s][c + 8];
            float mine = (lane & 8) ? acc[s][c + 8] : acc[s][c];
            acc[s][c] = mine + __shfl_xor(sent, 8, 64);
        }
        #pragma unroll
        for (int c = 0; c < 4; ++c) {
            float sent = (lane & 4) ? acc[s][c] : acc[s][c + 4];
            float mine = (lane & 4) ? acc[s][c + 4] : acc[s][c];
            acc[s][c] = mine + __shfl_xor(sent, 4, 64);
        }
        #pragma unroll
        for (int c = 0; c < 2; ++c) {
            float sent = (lane & 2) ? acc[s][c] : acc[s][c + 2];
            float mine = (lane & 2) ? acc[s][c + 2] : acc[s][c];
            acc[s][c] = mine + __shfl_xor(sent, 2, 64);
        }
        {
            float sent = (lane & 1) ? acc[s][0] : acc[s][1];
            float mine = (lane & 1) ? acc[s][1] : acc[s][0];
            acc[s][0] = mine + __shfl_xor(sent, 1, 64);
        }
    }
    // Route sample G to group G while finishing the cross-group reduction.
    const int g4 = (lane >> 4) & 1, g5 = (lane >> 5) & 1;
    float a01, a23, colsum;
    {
        float sent = g4 ? acc[0][0] : acc[1][0];
        float keep = g4 ? acc[1][0] : acc[0][0];
        a01 = keep + __shfl_xor(sent, 16, 64);
    }
    {
        float sent = g4 ? acc[2][0] : acc[3][0];
        float keep = g4 ? acc[3][0] : acc[2][0];
        a23 = keep + __shfl_xor(sent, 16, 64);
    }
    {
        float sent = g5 ? a01 : a23;
        float keep = g5 ? a23 : a01;
        colsum = keep + __shfl_xor(sent, 32, 64);   // group G owns sample G
    }

    part[wid][G][j] = colsum;
    __syncthreads();
    if (wid >= 2) return;

    // wave 0: samples bs+0..3 (waves 0+2); wave 1: samples bs+4..7 (1+3)
    colsum = part[wid][G][j] + part[wid + 2][G][j];

    float t0 = colsum + bin[j];
    float hj = t0 * rcpf(1.0f + expn(-t0));   // square_swish

    #pragma unroll
    for (int r = 0; r < cR; ++r) {
        const float* w1r = W1 + r * 256;
        const float* w2r = W2 + r * 256;
        float u = b1[r * 16 + j];
        #pragma unroll
        for (int i = 0; i < 16; ++i)
            u = fmaf(__shfl(hj, i, 16), w1r[i * 16 + j], u);
        u = u * rcpf(1.0f + expn(-u));
        float v = b2[r * 16 + j];
        #pragma unroll
        for (int i = 0; i < 16; ++i)
            v = fmaf(__shfl(u, i, 16), w2r[i * 16 + j], v);
        hj += v;
    }
    hbuf[(size_t)j * cB + (bs + wid * 4 + G)] = hj;   // transposed: [16][B]
}

// Invert the logistic-mixture logit per (sample b, dim d).
// Block = 256: 4 waves = 4 consecutive d (wave-uniform), lane = b in a 64-tile.
// ysrc = where y is read (eps for layers 3/2, z after); result written to z.
__global__ void __launch_bounds__(256) invert_kernel(
    float* __restrict__ z, const float* __restrict__ ysrc,
    const float* __restrict__ hbuf,
    const float* __restrict__ Wo, const float* __restrict__ bo,
    float* __restrict__ logq, int za_off)
{
    const int wid  = threadIdx.x >> 6;
    const int lane = threadIdx.x & 63;
    const int d = __builtin_amdgcn_readfirstlane(blockIdx.x * 4 + wid); // uniform
    const int b = blockIdx.y * 64 + lane;

    // h: 16 coalesced loads from transposed hbuf
    float hh[16];
    #pragma unroll
    for (int i = 0; i < 16; ++i) hh[i] = hbuf[(size_t)i * cB + b];

    // p[24] = bo[d*24+j] + sum_i h[i]*Wo[i*9408 + d*24 + j]  (Wo wave-uniform)
    float p[24];
    {
        const float4* bp = (const float4*)(bo + (size_t)d * 24);
        #pragma unroll
        for (int j4 = 0; j4 < 6; ++j4) {
            float4 v = bp[j4];
            p[j4*4+0] = v.x; p[j4*4+1] = v.y; p[j4*4+2] = v.z; p[j4*4+3] = v.w;
        }
        #pragma unroll
        for (int i = 0; i < 16; ++i) {
            float hv = hh[i];
            const float4* wr = (const float4*)(Wo + (size_t)i * cPDIM + (size_t)d * 24);
            #pragma unroll
            for (int j4 = 0; j4 < 6; ++j4) {
                float4 wv = wr[j4];
                p[j4*4+0] = fmaf(hv, wv.x, p[j4*4+0]);
                p[j4*4+1] = fmaf(hv, wv.y, p[j4*4+1]);
                p[j4*4+2] = fmaf(hv, wv.z, p[j4*4+2]);
                p[j4*4+3] = fmaf(hv, wv.w, p[j4*4+3]);
            }
        }
    }

    // Mirror: solve with mu_bar = sgn*mu, yb = |y|; x = sgn*x_bar.
    const float y0  = ysrc[(size_t)b * cD + za_off + d];
    const float sgn = (y0 < 0.f) ? -1.f : 1.f;
    const float yb  = fabsf(y0);

    // Unnormalized softmax weights wt (sum S); per-k prescaled scales.
    float wt[8], pm[8], q2[8], is2[8], nm2[8], wis2[8];
    float S, lgSn, SLN2, lo, hi;
    {
        float m = p[0];
        #pragma unroll
        for (int k = 1; k < 8; ++k) m = fmaxf(m, p[k]);
        S = 0.f;
        #pragma unroll
        for (int k = 0; k < 8; ++k) {
            pm[k] = p[k] - m;
            wt[k] = exp2f_(pm[k] * L2E_F);
            S += wt[k];
        }
        lgSn = log2f_(S) * LN2_F;   // ln S
        SLN2 = S * LN2_F;
        float lo0 = 1e30f, hi0 = -1e30f;
        #pragma unroll
        for (int k = 0; k < 8; ++k) {
            q2[k] = p[16 + k] * L2E_F;          // log2 s_k
            float sk  = exp2f_(q2[k]);          // s_k
            float ik  = exp2f_(-q2[k]);         // 1/s_k
            is2[k] = ik * L2E_F;
            float mub = sgn * p[8 + k];
            nm2[k] = -mub * is2[k];
            wis2[k] = wt[k] * is2[k];
            float inv = fmaf(yb, sk, mub);      // mu_bar + s_k*yb
            lo0 = fminf(lo0, inv); hi0 = fmaxf(hi0, inv);
        }
        float pad = 1e-3f + 1e-5f * (fabsf(lo0) + fabsf(hi0));
        lo = lo0 - pad; hi = hi0 + pad;
    }

    float xv, ld;
    if (yb <= 30.0f) {
        // tau*S with tau = sigmoid(-yb) >= ~5e-14
        float et   = exp2f_(-yb * L2E_F);
        float tauS = et * rcpf(1.0f + et) * S;
        // --- 2 bisections; r = 1/(1+exp2(t2)) = sigma(-t), overflow-exact
        #pragma unroll 1
        for (int it = 0; it < 2; ++it) {
            float mid = 0.5f * (lo + hi);
            float sfv = 0.f;
            #pragma unroll
            for (int k = 0; k < 8; ++k) {
                float t2 = fmaf(mid, is2[k], nm2[k]);
                float e  = exp2f_(t2);
                float r  = rcpf(1.0f + e);
                sfv = fmaf(wt[k], r, sfv);
            }
            if (sfv > tauS) lo = mid; else hi = mid;   // sf decreasing in x
        }
        // --- 3 bracketed Newton steps.  cdf = S - sfv (exact identity;
        // root has cdf >= S/2 after mirroring, so no catastrophic cancel);
        // sp*sn = r(1-r) = fma(-r,r,r) — no abs/selects needed.
        xv = 0.5f * (lo + hi);
        #pragma unroll 1
        for (int it = 0; it < 3; ++it) {
            float sfv = 0.f, pdfa = 0.f;
            #pragma unroll
            for (int k = 0; k < 8; ++k) {
                float t2 = fmaf(xv, is2[k], nm2[k]);
                float e  = exp2f_(t2);
                float r  = rcpf(1.0f + e);
                sfv  = fmaf(wt[k], r, sfv);
                pdfa = fmaf(wis2[k], fmaf(-r, r, r), pdfa);
            }
            float cdf = S - sfv;
            float f = (log2f_(cdf) - log2f_(sfv)) * LN2_F;
            if (f < yb) lo = xv; else hi = xv;
            float step = (f - yb) * cdf * sfv * rcpf(pdfa * SLN2);
            float xn = xv - step;
            if (!(xn > lo && xn < hi)) xn = 0.5f * (lo + hi);
            xv = xn;
        }
        // --- peeled eval: ld at xv (pre-step; step ~ eps) + final step
        {
            float sfv = 0.f, pdfa = 0.f;
            #pragma unroll
            for (int k = 0; k < 8; ++k) {
                float t2 = fmaf(xv, is2[k], nm2[k]);
                float e  = exp2f_(t2);
                float r  = rcpf(1.0f + e);
                sfv  = fmaf(wt[k], r, sfv);
                pdfa = fmaf(wis2[k], fmaf(-r, r, r), pdfa);
            }
            float cdf = S - sfv;
            float l2c = log2f_(cdf), l2s = log2f_(sfv), l2p = log2f_(pdfa);
            ld = (l2p - l2c - l2s) * LN2_F + LN_LN2_F + lgSn;
            float f = (l2c - l2s) * LN2_F;
            if (f < yb) lo = xv; else hi = xv;
            float step = (f - yb) * cdf * sfv * rcpf(pdfa * SLN2);
            float xn = xv - step;
            if (!(xn > lo && xn < hi)) xn = 0.5f * (lo + hi);
            xv = xn;
        }
    } else {
        // --- tail (yb>30): log-space LSE Newton from exact-bracket midpoint;
        // lc = log(1-sf) ~ -e^{-yb} ~ 0 (dropped, error < 1e-13).
        float lw[8], lis[8];
        #pragma unroll
        for (int k = 0; k < 8; ++k) {
            lw[k]  = pm[k] - lgSn;       // log softmax weight
            lis[k] = -q2[k] * LN2_F;     // -log s_k
        }
        xv = 0.5f * (lo + hi);
        #pragma unroll 1
        for (int it = 0; it < 4; ++it) {
            float u[8];
            float mu_ = -1e30f;
            #pragma unroll
            for (int k = 0; k < 8; ++k) {
                float t  = fmaf(xv, is2[k], nm2[k]) * LN2_F;  // natural t
                float ec = fminf(expn(-t), 1.0f);
                // log sigmoid(-t) = -t - log1p(e^{-t}) ~ -t - (ec - ec^2/2)
                u[k] = lw[k] - t - ec * fmaf(-0.5f, ec, 1.0f);
                mu_ = fmaxf(mu_, u[k]);
            }
            float Su = 0.f;
            #pragma unroll
            for (int k = 0; k < 8; ++k) Su += expn(u[k] - mu_);
            float lsf = mu_ + logn(Su);
            float m2 = -1e30f;
            #pragma unroll
            for (int k = 0; k < 8; ++k) m2 = fmaxf(m2, u[k] + lis[k]);
            float S2 = 0.f;
            #pragma unroll
            for (int k = 0; k < 8; ++k) S2 += expn(u[k] + lis[k] - m2);
            float lp = m2 + logn(S2);
            if (it == 3) { ld = lp - lsf; break; }
            float f = -lsf;                       // lc ~ 0
            if (f < yb) lo = xv; else hi = xv;
            float step = (f - yb) * expn(lsf - lp);
            float xn = xv - step;
            if (!(xn > lo && xn < hi)) xn = 0.5f * (lo + hi);
            xv = xn;
        }
    }

    z[(size_t)b * cD + za_off + d] = sgn * xv;

    // reduce ld over the 4 waves (4 d's) per b, one atomic per (block, b)
    __shared__ float red[256];
    red[threadIdx.x] = ld;
    __syncthreads();
    if (wid == 0) {
        float ssum = red[lane] + red[lane + 64] + red[lane + 128] + red[lane + 192];
        atomicAdd(&logq[b], ssum);
    }
}

extern "C" void kernel_launch(void* const* d_in, const int* in_sizes, int n_in,
                              void* d_out, int out_size, void* d_ws, size_t ws_size,
                              hipStream_t stream) {
    const float* x     = (const float*)d_in[0];
    const float* eps   = (const float*)d_in[1];
    const float* W_in  = (const float*)d_in[2];
    const float* b_in  = (const float*)d_in[3];
    const float* W1    = (const float*)d_in[4];
    const float* b1    = (const float*)d_in[5];
    const float* W2    = (const float*)d_in[6];
    const float* b2    = (const float*)d_in[7];
    const float* W_out = (const float*)d_in[8];
    const float* b_out = (const float*)d_in[9];

    float* z    = (float*)d_out;              // (B, D) working state = output z
    float* logq = z + (size_t)cB * cD;        // (B,)   output log_q
    float* hbuf = (float*)d_ws;               // (16, B) transposed scratch

    init_kernel<<<cB / 4, 256, 0, stream>>>(eps, logq);

    // Layer schedule (l = 3,2,1,0):
    //   l=3: zb = eps[:, 0:392],  y from eps[:, 392:784], write z[:, 392:784]
    //   l=2: zb = z  [:, 392:784], y from eps[:, 0:392],  write z[:, 0:392]
    //   l=1: zb = z  [:, 0:392],  y from z  [:, 392:784], write z[:, 392:784]
    //   l=0: zb = z  [:, 392:784], y from z  [:, 0:392],  write z[:, 0:392]
    for (int l = cL - 1; l >= 0; --l) {
        const int zb_off = (l & 1) ? 0 : cD1;
        const int za_off = (l & 1) ? cD1 : 0;
        const float* zbsrc = (l == 3) ? (eps + zb_off) : (z + zb_off);
        const float* ysrc  = (l >= 2) ? eps : z;
        mlp_kernel<<<cB / 8, 256, 0, stream>>>(
            zbsrc, x,
            W_in + (size_t)l * cDIN * cH, b_in + (size_t)l * cH,
            W1 + (size_t)l * cR * cH * cH, b1 + (size_t)l * cR * cH,
            W2 + (size_t)l * cR * cH * cH, b2 + (size_t)l * cR * cH,
            hbuf);
        invert_kernel<<<dim3(cD1 / 4, cB / 64), 256, 0, stream>>>(
            z, ysrc, hbuf,
            W_out + (size_t)l * cH * cPDIM, b_out + (size_t)l * cPDIM,
            logq, za_off);
    }
}

// Round 11
// 280.482 us; speedup vs baseline: 1.2309x; 1.0674x over previous
//
#include <hip/hip_runtime.h>
#include <math.h>

// Problem constants (from reference): B=4096, D=784, H=16, L=4, R=4, K=8
constexpr int cB   = 4096;
constexpr int cD   = 784;
constexpr int cD1  = 392;
constexpr int cH   = 16;
constexpr int cL   = 4;
constexpr int cR   = 4;
constexpr int cDIN = 1176;            // D1 + D
constexpr int cPDIM = cD1 * 3 * 8;    // 9408 = D1 * 3K
#define LOG2PI_F 1.8378770664093453f
#define L2E_F    1.4426950408889634f   // log2(e)
#define LN2_F    0.6931471805599453f   // ln(2)
#define LN_LN2_F (-0.36651292058166432701f) // ln(ln 2)

__device__ __forceinline__ float rcpf(float x)  { return __builtin_amdgcn_rcpf(x); }
__device__ __forceinline__ float exp2f_(float x){ return __builtin_amdgcn_exp2f(x); }
__device__ __forceinline__ float log2f_(float x){ return __builtin_amdgcn_logf(x); }
__device__ __forceinline__ float expn(float x)  { return exp2f_(x * L2E_F); }   // e^x
__device__ __forceinline__ float logn(float x)  { return log2f_(x) * LN2_F; }   // ln x

// log_q[b] = -0.5*sum(eps^2 + LOG2PI).  One wave/sample.  (No z copy: the
// four invert launches write every z element, layers 3/2 read y from eps.)
__global__ void __launch_bounds__(256) init_kernel(const float* __restrict__ eps,
                                                   float* __restrict__ logq) {
    const int wid  = threadIdx.x >> 6;
    const int lane = threadIdx.x & 63;
    const int b = blockIdx.x * 4 + wid;
    const float4* e = (const float4*)(eps + (size_t)b * cD);
    float sum = 0.f;
    for (int i = lane; i < cD / 4; i += 64) {   // 784 = 196 float4
        float4 v = e[i];
        sum = fmaf(v.x, v.x, sum); sum = fmaf(v.y, v.y, sum);
        sum = fmaf(v.z, v.z, sum); sum = fmaf(v.w, v.w, sum);
    }
    #pragma unroll
    for (int off = 32; off; off >>= 1) sum += __shfl_xor(sum, off, 64);
    if (lane == 0) logq[b] = -0.5f * sum - 0.5f * (float)cD * LOG2PI_F;
}

// h[16][b] (transposed) = conditioner MLP on concat(zb, x).
// v3 (best measured): 8 samples / block (4 waves).  Wave w: rows
// [588*(w>>1), +588) for samples (w&1)*4..+3 — split-K across wave pairs.
// Partials meet in 1 KB LDS; waves 0-1 run the residual net (4 samples each
// via width-16 shuffles).  zbsrc points at the zb half (z or eps).
__global__ void __launch_bounds__(256) mlp_kernel(
    const float* __restrict__ zbsrc, const float* __restrict__ x,
    const float* __restrict__ Win, const float* __restrict__ bin,
    const float* __restrict__ W1, const float* __restrict__ b1,
    const float* __restrict__ W2, const float* __restrict__ b2,
    float* __restrict__ hbuf)
{
    __shared__ float part[4][4][16];   // [wave][sample-in-group][col]
    const int wid  = threadIdx.x >> 6;
    const int lane = threadIdx.x & 63;
    const int j = lane & 15;
    const int G = lane >> 4;                      // 16-lane group 0..3
    const int bs = blockIdx.x * 8;                // block's first sample
    const int sb = bs + (wid & 1) * 4;            // wave's first sample
    const int r0 = (wid >> 1) * 588;              // wave's row range start

    float acc[4][16];
    #pragma unroll
    for (int s = 0; s < 4; ++s)
        #pragma unroll
        for (int c = 0; c < 16; ++c) acc[s][c] = 0.f;

    const float* pz[4]; const float* px[4];
    #pragma unroll
    for (int s = 0; s < 4; ++s) {
        pz[s] = zbsrc + (size_t)(sb + s) * cD;
        px[s] = x + (size_t)(sb + s) * cD - cD1;   // valid for i>=cD1
    }

    for (int i = r0 + lane; i < r0 + 588; i += 64) {
        const float4* wr = (const float4*)(Win + (size_t)i * cH);
        float4 w0 = wr[0], w1 = wr[1], w2 = wr[2], w3 = wr[3];
        float wv[16] = {w0.x,w0.y,w0.z,w0.w, w1.x,w1.y,w1.z,w1.w,
                        w2.x,w2.y,w2.z,w2.w, w3.x,w3.y,w3.z,w3.w};
        #pragma unroll
        for (int s = 0; s < 4; ++s) {
            const float* src = (i < cD1) ? pz[s] : px[s];
            float v = src[i];
            #pragma unroll
            for (int c = 0; c < 16; ++c) acc[s][c] = fmaf(v, wv[c], acc[s][c]);
        }
    }

    // Per-sample transpose-reduce (stages 8,4,2,1): lane ends holding col
    // (lane&15) of sample s, partial over its 16-lane group.
    #pragma unroll
    for (int s = 0; s < 4; ++s) {
        #pragma unroll
        for (int c = 0; c < 8; ++c) {
            float sent = (lane & 8) ? acc[s][c] : acc[s][c + 8];
            float mine = (lane & 8) ? acc[s][c + 8] : acc[s][c];
            acc[s][c] = mine + __shfl_xor(sent, 8, 64);
        }
        #pragma unroll
        for (int c = 0; c < 4; ++c) {
            float sent = (lane & 4) ? acc[s][c] : acc[s][c + 4];
            float mine = (lane & 4) ? acc[s][c + 4] : acc[s][c];
            acc[s][c] = mine + __shfl_xor(sent, 4, 64);
        }
        #pragma unroll
        for (int c = 0; c < 2; ++c) {
            float sent = (lane & 2) ? acc[s][c] : acc[s][c + 2];
            float mine = (lane & 2) ? acc[s][c + 2] : acc[s][c];
            acc[s][c] = mine + __shfl_xor(sent, 2, 64);
        }
        {
            float sent = (lane & 1) ? acc[s][0] : acc[s][1];
            float mine = (lane & 1) ? acc[s][1] : acc[s][0];
            acc[s][0] = mine + __shfl_xor(sent, 1, 64);
        }
    }
    // Route sample G to group G while finishing the cross-group reduction.
    const int g4 = (lane >> 4) & 1, g5 = (lane >> 5) & 1;
    float a01, a23, colsum;
    {
        float sent = g4 ? acc[0][0] : acc[1][0];
        float keep = g4 ? acc[1][0] : acc[0][0];
        a01 = keep + __shfl_xor(sent, 16, 64);
    }
    {
        float sent = g4 ? acc[2][0] : acc[3][0];
        float keep = g4 ? acc[3][0] : acc[2][0];
        a23 = keep + __shfl_xor(sent, 16, 64);
    }
    {
        float sent = g5 ? a01 : a23;
        float keep = g5 ? a23 : a01;
        colsum = keep + __shfl_xor(sent, 32, 64);   // group G owns sample G
    }

    part[wid][G][j] = colsum;
    __syncthreads();
    if (wid >= 2) return;

    // wave 0: samples bs+0..3 (waves 0+2); wave 1: samples bs+4..7 (1+3)
    colsum = part[wid][G][j] + part[wid + 2][G][j];

    float t0 = colsum + bin[j];
    float hj = t0 * rcpf(1.0f + expn(-t0));   // square_swish

    #pragma unroll
    for (int r = 0; r < cR; ++r) {
        const float* w1r = W1 + r * 256;
        const float* w2r = W2 + r * 256;
        float u = b1[r * 16 + j];
        #pragma unroll
        for (int i = 0; i < 16; ++i)
            u = fmaf(__shfl(hj, i, 16), w1r[i * 16 + j], u);
        u = u * rcpf(1.0f + expn(-u));
        float v = b2[r * 16 + j];
        #pragma unroll
        for (int i = 0; i < 16; ++i)
            v = fmaf(__shfl(u, i, 16), w2r[i * 16 + j], v);
        hj += v;
    }
    hbuf[(size_t)j * cB + (bs + wid * 4 + G)] = hj;   // transposed: [16][B]
}

// Invert the logistic-mixture logit per (sample b, dim d).
// Block = 256: 4 waves = 4 consecutive d (wave-uniform), lane = b in a 64-tile.
// ysrc = where y is read (eps for layers 3/2, z after); result written to z.
__global__ void __launch_bounds__(256) invert_kernel(
    float* __restrict__ z, const float* __restrict__ ysrc,
    const float* __restrict__ hbuf,
    const float* __restrict__ Wo, const float* __restrict__ bo,
    float* __restrict__ logq, int za_off)
{
    const int wid  = threadIdx.x >> 6;
    const int lane = threadIdx.x & 63;
    const int d = __builtin_amdgcn_readfirstlane(blockIdx.x * 4 + wid); // uniform
    const int b = blockIdx.y * 64 + lane;

    // h: 16 coalesced loads from transposed hbuf
    float hh[16];
    #pragma unroll
    for (int i = 0; i < 16; ++i) hh[i] = hbuf[(size_t)i * cB + b];

    // p[24] = bo[d*24+j] + sum_i h[i]*Wo[i*9408 + d*24 + j]  (Wo wave-uniform)
    float p[24];
    {
        const float4* bp = (const float4*)(bo + (size_t)d * 24);
        #pragma unroll
        for (int j4 = 0; j4 < 6; ++j4) {
            float4 v = bp[j4];
            p[j4*4+0] = v.x; p[j4*4+1] = v.y; p[j4*4+2] = v.z; p[j4*4+3] = v.w;
        }
        #pragma unroll
        for (int i = 0; i < 16; ++i) {
            float hv = hh[i];
            const float4* wr = (const float4*)(Wo + (size_t)i * cPDIM + (size_t)d * 24);
            #pragma unroll
            for (int j4 = 0; j4 < 6; ++j4) {
                float4 wv = wr[j4];
                p[j4*4+0] = fmaf(hv, wv.x, p[j4*4+0]);
                p[j4*4+1] = fmaf(hv, wv.y, p[j4*4+1]);
                p[j4*4+2] = fmaf(hv, wv.z, p[j4*4+2]);
                p[j4*4+3] = fmaf(hv, wv.w, p[j4*4+3]);
            }
        }
    }

    // Mirror: solve with mu_bar = sgn*mu, yb = |y|; x = sgn*x_bar.
    const float y0  = ysrc[(size_t)b * cD + za_off + d];
    const float sgn = (y0 < 0.f) ? -1.f : 1.f;
    const float yb  = fabsf(y0);

    // Unnormalized softmax weights wt (sum S); per-k prescaled scales.
    // Analytic bracket [min,max] of per-component inverses mu_bar + s_k*yb,
    // and the w-weighted mean of those inverses as the Newton seed x0.
    float wt[8], pm[8], q2[8], is2[8], nm2[8], wis2[8];
    float S, lgSn, SLN2, lo, hi, x0;
    {
        float m = p[0];
        #pragma unroll
        for (int k = 1; k < 8; ++k) m = fmaxf(m, p[k]);
        S = 0.f;
        #pragma unroll
        for (int k = 0; k < 8; ++k) {
            pm[k] = p[k] - m;
            wt[k] = exp2f_(pm[k] * L2E_F);
            S += wt[k];
        }
        lgSn = log2f_(S) * LN2_F;   // ln S
        SLN2 = S * LN2_F;
        float lo0 = 1e30f, hi0 = -1e30f, xa = 0.f;
        #pragma unroll
        for (int k = 0; k < 8; ++k) {
            q2[k] = p[16 + k] * L2E_F;          // log2 s_k
            float sk  = exp2f_(q2[k]);          // s_k
            float ik  = exp2f_(-q2[k]);         // 1/s_k
            is2[k] = ik * L2E_F;
            float mub = sgn * p[8 + k];
            nm2[k] = -mub * is2[k];
            wis2[k] = wt[k] * is2[k];
            float inv = fmaf(yb, sk, mub);      // mu_bar + s_k*yb
            lo0 = fminf(lo0, inv); hi0 = fmaxf(hi0, inv);
            xa = fmaf(wt[k], inv, xa);
        }
        float pad = 1e-3f + 1e-5f * (fabsf(lo0) + fabsf(hi0));
        lo = lo0 - pad; hi = hi0 + pad;
        x0 = xa * rcpf(S);                      // convex combo, inside bracket
    }

    float xv, ld;
    if (yb <= 30.0f) {
        // --- 3 bracket-safeguarded Newton steps from the weighted-mean seed.
        // cdf = S - sfv (exact; root has cdf >= S/2 after mirroring);
        // sp*sn = r(1-r) = fma(-r,r,r); r = 1/(1+exp2(t2)) overflow-exact.
        xv = x0;
        #pragma unroll 1
        for (int it = 0; it < 3; ++it) {
            float sfv = 0.f, pdfa = 0.f;
            #pragma unroll
            for (int k = 0; k < 8; ++k) {
                float t2 = fmaf(xv, is2[k], nm2[k]);
                float e  = exp2f_(t2);
                float r  = rcpf(1.0f + e);
                sfv  = fmaf(wt[k], r, sfv);
                pdfa = fmaf(wis2[k], fmaf(-r, r, r), pdfa);
            }
            float cdf = S - sfv;
            float f = (log2f_(cdf) - log2f_(sfv)) * LN2_F;
            if (f < yb) lo = xv; else hi = xv;
            float step = (f - yb) * cdf * sfv * rcpf(pdfa * SLN2);
            float xn = xv - step;
            if (!(xn > lo && xn < hi)) xn = 0.5f * (lo + hi);
            xv = xn;
        }
        // --- peeled eval: ld at xv (pre-step; step ~ eps) + final step
        {
            float sfv = 0.f, pdfa = 0.f;
            #pragma unroll
            for (int k = 0; k < 8; ++k) {
                float t2 = fmaf(xv, is2[k], nm2[k]);
                float e  = exp2f_(t2);
                float r  = rcpf(1.0f + e);
                sfv  = fmaf(wt[k], r, sfv);
                pdfa = fmaf(wis2[k], fmaf(-r, r, r), pdfa);
            }
            float cdf = S - sfv;
            float l2c = log2f_(cdf), l2s = log2f_(sfv), l2p = log2f_(pdfa);
            ld = (l2p - l2c - l2s) * LN2_F + LN_LN2_F + lgSn;
            float f = (l2c - l2s) * LN2_F;
            if (f < yb) lo = xv; else hi = xv;
            float step = (f - yb) * cdf * sfv * rcpf(pdfa * SLN2);
            float xn = xv - step;
            if (!(xn > lo && xn < hi)) xn = 0.5f * (lo + hi);
            xv = xn;
        }
    } else {
        // --- tail (yb>30): log-space LSE Newton from the weighted-mean seed;
        // lc = log(1-sf) ~ -e^{-yb} ~ 0 (dropped, error < 1e-13).
        float lw[8], lis[8];
        #pragma unroll
        for (int k = 0; k < 8; ++k) {
            lw[k]  = pm[k] - lgSn;       // log softmax weight
            lis[k] = -q2[k] * LN2_F;     // -log s_k
        }
        xv = x0;
        #pragma unroll 1
        for (int it = 0; it < 4; ++it) {
            float u[8];
            float mu_ = -1e30f;
            #pragma unroll
            for (int k = 0; k < 8; ++k) {
                float t  = fmaf(xv, is2[k], nm2[k]) * LN2_F;  // natural t
                float ec = fminf(expn(-t), 1.0f);
                // log sigmoid(-t) = -t - log1p(e^{-t}) ~ -t - (ec - ec^2/2)
                u[k] = lw[k] - t - ec * fmaf(-0.5f, ec, 1.0f);
                mu_ = fmaxf(mu_, u[k]);
            }
            float Su = 0.f;
            #pragma unroll
            for (int k = 0; k < 8; ++k) Su += expn(u[k] - mu_);
            float lsf = mu_ + logn(Su);
            float m2 = -1e30f;
            #pragma unroll
            for (int k = 0; k < 8; ++k) m2 = fmaxf(m2, u[k] + lis[k]);
            float S2 = 0.f;
            #pragma unroll
            for (int k = 0; k < 8; ++k) S2 += expn(u[k] + lis[k] - m2);
            float lp = m2 + logn(S2);
            if (it == 3) { ld = lp - lsf; break; }
            float f = -lsf;                       // lc ~ 0
            if (f < yb) lo = xv; else hi = xv;
            float step = (f - yb) * expn(lsf - lp);
            float xn = xv - step;
            if (!(xn > lo && xn < hi)) xn = 0.5f * (lo + hi);
            xv = xn;
        }
    }

    z[(size_t)b * cD + za_off + d] = sgn * xv;

    // reduce ld over the 4 waves (4 d's) per b, one atomic per (block, b)
    __shared__ float red[256];
    red[threadIdx.x] = ld;
    __syncthreads();
    if (wid == 0) {
        float ssum = red[lane] + red[lane + 64] + red[lane + 128] + red[lane + 192];
        atomicAdd(&logq[b], ssum);
    }
}

extern "C" void kernel_launch(void* const* d_in, const int* in_sizes, int n_in,
                              void* d_out, int out_size, void* d_ws, size_t ws_size,
                              hipStream_t stream) {
    const float* x     = (const float*)d_in[0];
    const float* eps   = (const float*)d_in[1];
    const float* W_in  = (const float*)d_in[2];
    const float* b_in  = (const float*)d_in[3];
    const float* W1    = (const float*)d_in[4];
    const float* b1    = (const float*)d_in[5];
    const float* W2    = (const float*)d_in[6];
    const float* b2    = (const float*)d_in[7];
    const float* W_out = (const float*)d_in[8];
    const float* b_out = (const float*)d_in[9];

    float* z    = (float*)d_out;              // (B, D) working state = output z
    float* logq = z + (size_t)cB * cD;        // (B,)   output log_q
    float* hbuf = (float*)d_ws;               // (16, B) transposed scratch

    init_kernel<<<cB / 4, 256, 0, stream>>>(eps, logq);

    // Layer schedule (l = 3,2,1,0):
    //   l=3: zb = eps[:, 0:392],  y from eps[:, 392:784], write z[:, 392:784]
    //   l=2: zb = z  [:, 392:784], y from eps[:, 0:392],  write z[:, 0:392]
    //   l=1: zb = z  [:, 0:392],  y from z  [:, 392:784], write z[:, 392:784]
    //   l=0: zb = z  [:, 392:784], y from z  [:, 0:392],  write z[:, 0:392]
    for (int l = cL - 1; l >= 0; --l) {
        const int zb_off = (l & 1) ? 0 : cD1;
        const int za_off = (l & 1) ? cD1 : 0;
        const float* zbsrc = (l == 3) ? (eps + zb_off) : (z + zb_off);
        const float* ysrc  = (l >= 2) ? eps : z;
        mlp_kernel<<<cB / 8, 256, 0, stream>>>(
            zbsrc, x,
            W_in + (size_t)l * cDIN * cH, b_in + (size_t)l * cH,
            W1 + (size_t)l * cR * cH * cH, b1 + (size_t)l * cR * cH,
            W2 + (size_t)l * cR * cH * cH, b2 + (size_t)l * cR * cH,
            hbuf);
        invert_kernel<<<dim3(cD1 / 4, cB / 64), 256, 0, stream>>>(
            z, ysrc, hbuf,
            W_out + (size_t)l * cH * cPDIM, b_out + (size_t)l * cPDIM,
            logq, za_off);
    }
}